// Round 1
// baseline (423.187 us; speedup 1.0000x reference)
//
#include <hip/hip_runtime.h>

// reset_layer: Out = R^T · X_grid · L^T + X per pixel-group, x (16,2000,2000)
// fp32, bs=10 (no padding). Block = one (b,h) "row line": the 10 image rows
// {h + ih*200}, each a contiguous 8 KB span.
//
// v3: phase-B remap kills the 10x LDS read amplification of v2.
//   A: thread (ih,wo4) holds its 40-float X row-slice in registers, does the
//      W-mix (Y = X·L^T) in-register, writes Y to LDS (10 ds_write_b128).
//   B: thread re-mapped to column (jwq=t/50, wo4=t%50): reads the 10
//      Y[ihp][jwq][wo4] values ONCE each (10 ds_read_b128, fully contiguous
//      1024B/wave), accumulates all 10 jh outputs in registers (10x register
//      reuse per read), and overwrites its own 10 slots in place (disjoint
//      across threads; same-thread RAW ordered through registers -> no
//      barrier between read and write).
//   C: thread (ih,wo4) reads back its Z row (10 reads), adds the identity
//      x4[] still resident in registers, stores contiguously.
// LDS ops/thread: 110 -> 40. Global pattern identical to v2. R coefficients
// are loop-uniform -> s_load; the Rts LDS transpose buffer is gone.

#define IMG   2000
#define BSZ   10
#define TC    200                 // chunk size = 2000/10
#define CHW   (IMG * IMG)         // 4,000,000
#define NW4   (TC / 4)            // 50 float4 slots per chunk-row slice

__global__ __launch_bounds__(512, 4)
void reset_rowline3(const float* __restrict__ x,
                    const float* __restrict__ leftm,
                    const float* __restrict__ rightm,
                    float* __restrict__ out)
{
    // Y/Z[idx10][jw or jwq][wo4] : 10*10*50 float4 = 80,000 B
    __shared__ __align__(16) float4 Ysh[BSZ * BSZ * NW4];

    const int t   = threadIdx.x;
    const int bid = blockIdx.x;        // 0..3199
    const int b   = bid / TC;          // batch index
    const int h   = bid % TC;          // intra-chunk row offset

    const int  ih     = t / NW4;       // 0..9  (valid for t < 500)
    const int  wo4    = t - ih * NW4;  // 0..49
    const bool active = (t < BSZ * NW4);

    // ---- load X row-slice: 10 float4s, ~800-1024B contiguous per wave-inst
    float4 x4[BSZ];
    if (active) {
        const float4* rowp =
            (const float4*)(x + (size_t)b * CHW + (size_t)(ih * TC + h) * IMG);
        #pragma unroll
        for (int iw = 0; iw < BSZ; ++iw)
            x4[iw] = rowp[iw * NW4 + wo4];

        // ---- phase A: Y[ih][jw][wo4] = sum_iw L[jw][iw] * x4[iw]
        // L indices are compile-time + uniform -> s_load (SGPR).
        #pragma unroll
        for (int jw = 0; jw < BSZ; ++jw) {
            const float l0 = leftm[jw * BSZ + 0];
            float4 y;
            y.x = l0 * x4[0].x; y.y = l0 * x4[0].y;
            y.z = l0 * x4[0].z; y.w = l0 * x4[0].w;
            #pragma unroll
            for (int iw = 1; iw < BSZ; ++iw) {
                const float l = leftm[jw * BSZ + iw];
                y.x += l * x4[iw].x; y.y += l * x4[iw].y;
                y.z += l * x4[iw].z; y.w += l * x4[iw].w;
            }
            Ysh[(ih * BSZ + jw) * NW4 + wo4] = y;
        }
    }

    __syncthreads();

    // ---- phase B: thread owns column (jwq, wo4); z[jh] = sum_ihp Rt * Y
    // Read addresses flatten to ihp*8000 + t*16 bytes: one contiguous 1024B
    // segment per wave per ihp. Each read feeds all 10 jh accumulators.
    if (active) {
        const int jwq = ih;            // t/50: reuse the phase-A partition
        float4 z[BSZ];
        {
            const float4 yv = Ysh[(0 * BSZ + jwq) * NW4 + wo4];
            #pragma unroll
            for (int jh = 0; jh < BSZ; ++jh) {
                const float r = rightm[0 * BSZ + jh];   // R[ihp][jh], uniform
                z[jh].x = r * yv.x; z[jh].y = r * yv.y;
                z[jh].z = r * yv.z; z[jh].w = r * yv.w;
            }
        }
        #pragma unroll
        for (int ihp = 1; ihp < BSZ; ++ihp) {
            const float4 yv = Ysh[(ihp * BSZ + jwq) * NW4 + wo4];
            #pragma unroll
            for (int jh = 0; jh < BSZ; ++jh) {
                const float r = rightm[ihp * BSZ + jh];
                z[jh].x += r * yv.x; z[jh].y += r * yv.y;
                z[jh].z += r * yv.z; z[jh].w += r * yv.w;
            }
        }
        // overwrite own column slots in place: the 500 threads partition the
        // 5000 slots bijectively; writes depend on all reads via registers.
        #pragma unroll
        for (int jh = 0; jh < BSZ; ++jh)
            Ysh[(jh * BSZ + jwq) * NW4 + wo4] = z[jh];
    }

    __syncthreads();

    // ---- phase C: add resident identity, store contiguous 1024B/wave-inst
    if (active) {
        float4* orow =
            (float4*)(out + (size_t)b * CHW + (size_t)(ih * TC + h) * IMG);
        #pragma unroll
        for (int jw = 0; jw < BSZ; ++jw) {
            float4 zv = Ysh[(ih * BSZ + jw) * NW4 + wo4];
            zv.x += x4[jw].x; zv.y += x4[jw].y;
            zv.z += x4[jw].z; zv.w += x4[jw].w;
            orow[jw * NW4 + wo4] = zv;
        }
    }
}

extern "C" void kernel_launch(void* const* d_in, const int* in_sizes, int n_in,
                              void* d_out, int out_size, void* d_ws, size_t ws_size,
                              hipStream_t stream) {
    const float* x = (const float*)d_in[0];
    const float* L = (const float*)d_in[1];
    const float* R = (const float*)d_in[2];
    float* out = (float*)d_out;
    // one block per (b, h): 16 * 200 = 3200 blocks, 512 threads (500 active)
    reset_rowline3<<<3200, 512, 0, stream>>>(x, L, R, out);
}